// Round 1
// baseline (1513.661 us; speedup 1.0000x reference)
//
#include <hip/hip_runtime.h>
#include <hip/hip_bf16.h>

#define BB 128
#define NN 4096
#define DD 64
#define SS 8
#define HH 128

__device__ __forceinline__ float warp_red_sum(float v) {
    #pragma unroll
    for (int off = 32; off; off >>= 1) v += __shfl_xor(v, off);
    return v;
}

__device__ __forceinline__ float bcastlane(float v, int l) {
    return __int_as_float(__builtin_amdgcn_readlane(__float_as_int(v), l));
}

__device__ __forceinline__ void unp2(unsigned u, float& a, float& b) {
    union { unsigned q; float f; } t0, t1;
    t0.q = u << 16; t1.q = u & 0xffff0000u;
    a = t0.f; b = t1.f;
}

// ---------------- prep: transpose weights (fold 1/sqrt(D) into kwT) ----------------
__global__ __launch_bounds__(256) void prep_kernel(
    const float* __restrict__ k_w, const float* __restrict__ v_w, const float* __restrict__ q_w,
    const float* __restrict__ wih, const float* __restrict__ whh,
    const float* __restrict__ w1, const float* __restrict__ w2,
    float* __restrict__ kwT, float* __restrict__ vwT, float* __restrict__ qwT,
    float* __restrict__ wihT, float* __restrict__ whhT,
    float* __restrict__ w1T, float* __restrict__ w2T)
{
    int i0 = blockIdx.x * blockDim.x + threadIdx.x;
    int nthr = gridDim.x * blockDim.x;
    for (int t = i0; t < 4096; t += nthr) {
        int r = t >> 6, c = t & 63;           // t = i*64 + d
        kwT[t] = k_w[c * 64 + r] * 0.125f;
        vwT[t] = v_w[c * 64 + r];
        qwT[t] = q_w[c * 64 + r];
    }
    for (int t = i0; t < 12288; t += nthr) {
        int r = t / 192, c = t % 192;         // t = i*192 + g
        wihT[t] = wih[c * 64 + r];
        whhT[t] = whh[c * 64 + r];
    }
    for (int t = i0; t < 8192; t += nthr) {
        int r = t >> 7, c = t & 127;          // t = i*128 + j
        w1T[t] = w1[c * 64 + r];
    }
    for (int t = i0; t < 8192; t += nthr) {
        int r = t >> 6, c = t & 63;           // t = j*64 + d
        w2T[t] = w2[c * 128 + r];
    }
}

// ---------------- slots init ----------------
__global__ __launch_bounds__(256) void slots_init_kernel(
    const float* __restrict__ eps, const float* __restrict__ mu,
    const float* __restrict__ lv, float* __restrict__ slots)
{
    int idx = blockIdx.x * blockDim.x + threadIdx.x;   // 65536 exact
    int d = idx & 63;
    slots[idx] = mu[d] + __expf(0.5f * lv[d]) * eps[idx];
}

// ---------------- phase A: LN + k/v projections, bf16 out ----------------
__global__ __launch_bounds__(256) void phase_a_kernel(
    const float* __restrict__ inp, const float* __restrict__ kwT_g, const float* __restrict__ vwT_g,
    const float* __restrict__ niw, const float* __restrict__ nib,
    __hip_bfloat16* __restrict__ kb, __hip_bfloat16* __restrict__ vb)
{
    __shared__ float kw[4096];
    __shared__ float vw[4096];
    const int tid = threadIdx.x;
    for (int t = tid; t < 4096; t += 256) { kw[t] = kwT_g[t]; vw[t] = vwT_g[t]; }
    __syncthreads();
    const int lane = tid & 63, widx = tid >> 6;
    const int wave = blockIdx.x * 4 + widx;            // grid 2048 -> 8192 waves
    const float w_ni = niw[lane], b_ni = nib[lane];
    const int base_t = wave * 64;                      // 64 tokens per wave
    for (int it = 0; it < 64; ++it) {
        const int tok = base_t + it;
        float x = inp[(size_t)tok * 64 + lane];
        float m = warp_red_sum(x) * (1.0f / 64.0f);
        float dx = x - m;
        float var = warp_red_sum(dx * dx) * (1.0f / 64.0f);
        float xln = dx * rsqrtf(var + 1e-5f) * w_ni + b_ni;
        float ak = 0.f, av = 0.f;
        #pragma unroll 16
        for (int i = 0; i < 64; ++i) {
            float xi = bcastlane(xln, i);
            ak = fmaf(xi, kw[i * 64 + lane], ak);
            av = fmaf(xi, vw[i * 64 + lane], av);
        }
        kb[(size_t)tok * 64 + lane] = __float2bfloat16(ak);
        vb[(size_t)tok * 64 + lane] = __float2bfloat16(av);
    }
}

// ---------------- q = LN(slots) @ q_w.T ----------------
__global__ __launch_bounds__(256) void q_kernel(
    const float* __restrict__ slots, const float* __restrict__ qwT,
    const float* __restrict__ nsw, const float* __restrict__ nsb, float* __restrict__ qout)
{
    const int lane = threadIdx.x & 63;
    const int row = blockIdx.x * 4 + (threadIdx.x >> 6);   // grid 256 -> 1024 rows
    float x = slots[row * 64 + lane];
    float m = warp_red_sum(x) * (1.0f / 64.0f);
    float dx = x - m;
    float var = warp_red_sum(dx * dx) * (1.0f / 64.0f);
    float xln = dx * rsqrtf(var + 1e-5f) * nsw[lane] + nsb[lane];
    float acc = 0.f;
    #pragma unroll 16
    for (int i = 0; i < 64; ++i) acc = fmaf(bcastlane(xln, i), qwT[i * 64 + lane], acc);
    qout[row * 64 + lane] = acc;
}

// ---------------- attention: logits -> softmax+EPS -> accumulate numer/denom ----------------
__global__ __launch_bounds__(256) void attn_kernel(
    const __hip_bfloat16* __restrict__ kb, const __hip_bfloat16* __restrict__ vb,
    const float* __restrict__ qbuf, float* __restrict__ numer, float* __restrict__ denom,
    float* __restrict__ wout)
{
    __shared__ float q_lds[512];
    __shared__ float red[2048];
    __shared__ float dred[32];
    const int tid = threadIdx.x, lane = tid & 63, widx = tid >> 6;
    const int b = blockIdx.y, chunk = blockIdx.x;      // grid (8,128): 512 tokens per block
    for (int t = tid; t < 512; t += 256) q_lds[t] = qbuf[b * 512 + t];
    __syncthreads();

    float nm[8], dsum[8];
    #pragma unroll
    for (int s = 0; s < 8; ++s) { nm[s] = 0.f; dsum[s] = 0.f; }

    #pragma unroll 1
    for (int itr = 0; itr < 2; ++itr) {
        const int gbase = chunk * 512 + itr * 256 + widx * 64;
        const int tok = gbase + lane;
        // each lane loads its own token's k row (64 bf16)
        float kr[64];
        const uint4* kp = reinterpret_cast<const uint4*>(kb + ((size_t)b * NN + tok) * 64);
        #pragma unroll
        for (int c = 0; c < 8; ++c) {
            uint4 u = kp[c];
            unp2(u.x, kr[c * 8 + 0], kr[c * 8 + 1]);
            unp2(u.y, kr[c * 8 + 2], kr[c * 8 + 3]);
            unp2(u.z, kr[c * 8 + 4], kr[c * 8 + 5]);
            unp2(u.w, kr[c * 8 + 6], kr[c * 8 + 7]);
        }
        float wv[8];
        #pragma unroll
        for (int s = 0; s < 8; ++s) {
            float acc = 0.f;
            #pragma unroll
            for (int i = 0; i < 64; ++i) acc = fmaf(kr[i], q_lds[s * 64 + i], acc);
            wv[s] = acc;
        }
        float mx = wv[0];
        #pragma unroll
        for (int s = 1; s < 8; ++s) mx = fmaxf(mx, wv[s]);
        float sum = 0.f;
        #pragma unroll
        for (int s = 0; s < 8; ++s) { wv[s] = __expf(wv[s] - mx); sum += wv[s]; }
        float rs = 1.0f / sum;
        #pragma unroll
        for (int s = 0; s < 8; ++s) { wv[s] = fmaf(wv[s], rs, 1e-8f); dsum[s] += wv[s]; }
        if (wout) {
            float4* wp = reinterpret_cast<float4*>(wout + ((size_t)b * NN + tok) * 8);
            wp[0] = make_float4(wv[0], wv[1], wv[2], wv[3]);
            wp[1] = make_float4(wv[4], wv[5], wv[6], wv[7]);
        }
        // numer accumulation: lane = d
        const __hip_bfloat16* vbase = vb + ((size_t)b * NN + gbase) * 64;
        #pragma unroll 8
        for (int t2 = 0; t2 < 64; ++t2) {
            float vv = __bfloat162float(vbase[t2 * 64 + lane]);
            #pragma unroll
            for (int s = 0; s < 8; ++s) nm[s] = fmaf(bcastlane(wv[s], t2), vv, nm[s]);
        }
    }

    // block-level reduction, then one atomic pass
    #pragma unroll
    for (int s = 0; s < 8; ++s) red[widx * 512 + s * 64 + lane] = nm[s];
    #pragma unroll
    for (int s = 0; s < 8; ++s) dsum[s] = warp_red_sum(dsum[s]);
    if (lane == 0) {
        #pragma unroll
        for (int s = 0; s < 8; ++s) dred[widx * 8 + s] = dsum[s];
    }
    __syncthreads();
    for (int e = tid; e < 512; e += 256) {
        float v = red[e] + red[512 + e] + red[1024 + e] + red[1536 + e];
        atomicAdd(numer + (size_t)b * 512 + e, v);
    }
    if (tid < 8) atomicAdd(denom + b * 8 + tid,
                           dred[tid] + dred[8 + tid] + dred[16 + tid] + dred[24 + tid]);
}

// ---------------- GRU + MLP per slot row ----------------
__global__ __launch_bounds__(256) void gru_kernel(
    const float* __restrict__ numer, const float* __restrict__ denom,
    const float* __restrict__ slotsIn,
    const float* __restrict__ wihT, const float* __restrict__ whhT,
    const float* __restrict__ w1T, const float* __restrict__ w2T,
    const float* __restrict__ bih, const float* __restrict__ bhh,
    const float* __restrict__ nrw, const float* __restrict__ nrb,
    const float* __restrict__ b2, float* __restrict__ slotsOut)
{
    const int lane = threadIdx.x & 63;
    const int row = blockIdx.x * 4 + (threadIdx.x >> 6);   // grid 256 -> 1024 rows
    float x = numer[row * 64 + lane] / denom[row];
    float h = slotsIn[row * 64 + lane];
    float air = 0, aiz = 0, ain = 0, ahr = 0, ahz = 0, ahn = 0;
    #pragma unroll 8
    for (int i = 0; i < 64; ++i) {
        float xi = bcastlane(x, i), hi = bcastlane(h, i);
        const float* wi = wihT + i * 192;
        const float* wh = whhT + i * 192;
        air = fmaf(xi, wi[lane], air);
        aiz = fmaf(xi, wi[64 + lane], aiz);
        ain = fmaf(xi, wi[128 + lane], ain);
        ahr = fmaf(hi, wh[lane], ahr);
        ahz = fmaf(hi, wh[64 + lane], ahz);
        ahn = fmaf(hi, wh[128 + lane], ahn);
    }
    air += bih[lane]; aiz += bih[64 + lane]; ain += bih[128 + lane];
    ahr += bhh[lane]; ahz += bhh[64 + lane]; ahn += bhh[128 + lane];
    float r = 1.f / (1.f + __expf(-(air + ahr)));
    float z = 1.f / (1.f + __expf(-(aiz + ahz)));
    float n = tanhf(ain + r * ahn);
    float hn = (1.f - z) * n + z * h;
    // LN + MLP residual
    float m = warp_red_sum(hn) * (1.0f / 64.0f);
    float dx = hn - m;
    float var = warp_red_sum(dx * dx) * (1.0f / 64.0f);
    float u = dx * rsqrtf(var + 1e-5f) * nrw[lane] + nrb[lane];
    float o0 = 0.f, o1 = 0.f;
    #pragma unroll 8
    for (int i = 0; i < 64; ++i) {
        float ui = bcastlane(u, i);
        const float* w1r = w1T + i * 128;
        o0 = fmaf(ui, w1r[lane], o0);
        o1 = fmaf(ui, w1r[64 + lane], o1);
    }
    o0 = fmaxf(o0, 0.f); o1 = fmaxf(o1, 0.f);
    float y = 0.f;
    #pragma unroll 8
    for (int j = 0; j < 64; ++j) y = fmaf(bcastlane(o0, j), w2T[j * 64 + lane], y);
    #pragma unroll 8
    for (int j = 0; j < 64; ++j) y = fmaf(bcastlane(o1, j), w2T[(64 + j) * 64 + lane], y);
    y += b2[lane];
    slotsOut[row * 64 + lane] = hn + y;
}

// ---------------- final renorm of w output ----------------
__global__ __launch_bounds__(256) void renorm_kernel(float* __restrict__ wout,
                                                     const float* __restrict__ denom)
{
    const size_t i4 = (size_t)blockIdx.x * blockDim.x + threadIdx.x;  // 1,048,576 float4s
    const size_t b = i4 >> 13;
    const int half = (int)(i4 & 1);
    float4 v = reinterpret_cast<float4*>(wout)[i4];
    const float4 dv = reinterpret_cast<const float4*>(denom)[b * 2 + half];
    v.x /= dv.x; v.y /= dv.y; v.z /= dv.z; v.w /= dv.w;
    reinterpret_cast<float4*>(wout)[i4] = v;
}

extern "C" void kernel_launch(void* const* d_in, const int* in_sizes, int n_in,
                              void* d_out, int out_size, void* d_ws, size_t ws_size,
                              hipStream_t stream)
{
    const float* inputs  = (const float*)d_in[0];
    const float* eps_n   = (const float*)d_in[1];
    const float* mu      = (const float*)d_in[2];
    const float* lv      = (const float*)d_in[3];
    const float* k_w     = (const float*)d_in[4];
    const float* v_w     = (const float*)d_in[5];
    const float* q_w     = (const float*)d_in[6];
    const float* ni_w    = (const float*)d_in[7];
    const float* ni_b    = (const float*)d_in[8];
    const float* ns_w    = (const float*)d_in[9];
    const float* ns_b    = (const float*)d_in[10];
    const float* nr_w    = (const float*)d_in[11];
    const float* nr_b    = (const float*)d_in[12];
    const float* gru_wih = (const float*)d_in[13];
    const float* gru_whh = (const float*)d_in[14];
    const float* gru_bih = (const float*)d_in[15];
    const float* gru_bhh = (const float*)d_in[16];
    const float* mlp_w1  = (const float*)d_in[17];
    const float* mlp_w2  = (const float*)d_in[18];
    const float* mlp_b2  = (const float*)d_in[19];

    char* wsb = (char*)d_ws;
    __hip_bfloat16* kb = (__hip_bfloat16*)wsb;                       // 67,108,864 B
    __hip_bfloat16* vb = (__hip_bfloat16*)(wsb + 67108864);          // 67,108,864 B
    float* f      = (float*)(wsb + 134217728);
    float* slotsA = f;                  // 65536
    float* slotsB = f + 65536;          // 65536
    float* qbuf   = f + 131072;         // 65536
    float* numer  = f + 196608;         // 65536
    float* denom  = f + 262144;         // 1024
    float* kwT    = f + 263168;         // 4096
    float* vwT    = kwT + 4096;
    float* qwT    = vwT + 4096;
    float* wihT   = qwT + 4096;         // 12288
    float* whhT   = wihT + 12288;       // 12288
    float* w1T    = whhT + 12288;       // 8192
    float* w2T    = w1T + 8192;         // 8192

    float* out_slots = (float*)d_out;
    float* out_w     = out_slots + 65536;

    prep_kernel<<<64, 256, 0, stream>>>(k_w, v_w, q_w, gru_wih, gru_whh, mlp_w1, mlp_w2,
                                        kwT, vwT, qwT, wihT, whhT, w1T, w2T);
    slots_init_kernel<<<256, 256, 0, stream>>>(eps_n, mu, lv, slotsA);
    phase_a_kernel<<<2048, 256, 0, stream>>>(inputs, kwT, vwT, ni_w, ni_b, kb, vb);

    float* cur = slotsA;
    for (int step = 0; step < 4; ++step) {
        hipMemsetAsync(numer, 0, (65536 + 1024) * sizeof(float), stream);
        q_kernel<<<256, 256, 0, stream>>>(cur, qwT, ns_w, ns_b, qbuf);
        attn_kernel<<<dim3(8, 128), 256, 0, stream>>>(kb, vb, qbuf, numer, denom,
                                                      step == 3 ? out_w : nullptr);
        float* nxt = (step == 3) ? out_slots : ((step & 1) ? slotsA : slotsB);
        gru_kernel<<<256, 256, 0, stream>>>(numer, denom, cur, wihT, whhT, w1T, w2T,
                                            gru_bih, gru_bhh, nr_w, nr_b, mlp_b2, nxt);
        cur = nxt;
    }
    renorm_kernel<<<4096, 256, 0, stream>>>(out_w, denom);
}

// Round 2
// 1254.936 us; speedup vs baseline: 1.2062x; 1.2062x over previous
//
#include <hip/hip_runtime.h>
#include <hip/hip_bf16.h>

#define BB 128
#define NN 4096
#define DD 64
#define SS 8
#define HH 128

typedef __attribute__((ext_vector_type(8))) short short8;
typedef __attribute__((ext_vector_type(4))) float f32x4;

__device__ __forceinline__ float warp_red_sum(float v) {
    #pragma unroll
    for (int off = 32; off; off >>= 1) v += __shfl_xor(v, off);
    return v;
}

__device__ __forceinline__ float bcastlane(float v, int l) {
    return __int_as_float(__builtin_amdgcn_readlane(__float_as_int(v), l));
}

__device__ __forceinline__ void unp2(unsigned u, float& a, float& b) {
    union { unsigned q; float f; } t0, t1;
    t0.q = u << 16; t1.q = u & 0xffff0000u;
    a = t0.f; b = t1.f;
}

// ---------------- prep: weight transposes + bf16 [kw*0.125 ; vw] cat ----------------
__global__ __launch_bounds__(256) void prep_kernel(
    const float* __restrict__ k_w, const float* __restrict__ v_w, const float* __restrict__ q_w,
    const float* __restrict__ wih, const float* __restrict__ whh,
    const float* __restrict__ w1, const float* __restrict__ w2,
    unsigned short* __restrict__ wcat, float* __restrict__ qwT,
    float* __restrict__ wihT, float* __restrict__ whhT,
    float* __restrict__ w1T, float* __restrict__ w2T)
{
    int i0 = blockIdx.x * blockDim.x + threadIdx.x;
    int nthr = gridDim.x * blockDim.x;
    // wcat[n][k], n in [0,128): rows 0..63 = k_w * 0.125, rows 64..127 = v_w. bf16.
    for (int t = i0; t < 8192; t += nthr) {
        int n = t >> 6, k = t & 63;
        float val = (n < 64) ? k_w[n * 64 + k] * 0.125f : v_w[(n - 64) * 64 + k];
        __hip_bfloat16 h = __float2bfloat16(val);
        wcat[t] = *(unsigned short*)&h;
    }
    for (int t = i0; t < 4096; t += nthr) {
        int r = t >> 6, c = t & 63;           // t = i*64 + d
        qwT[t] = q_w[c * 64 + r];
    }
    for (int t = i0; t < 12288; t += nthr) {
        int r = t / 192, c = t % 192;         // t = i*192 + g
        wihT[t] = wih[c * 64 + r];
        whhT[t] = whh[c * 64 + r];
    }
    for (int t = i0; t < 8192; t += nthr) {
        int r = t >> 7, c = t & 127;          // t = i*128 + j
        w1T[t] = w1[c * 64 + r];
    }
    for (int t = i0; t < 8192; t += nthr) {
        int r = t >> 6, c = t & 63;           // t = j*64 + d
        w2T[t] = w2[c * 128 + r];
    }
}

// ---------------- slots init ----------------
__global__ __launch_bounds__(256) void slots_init_kernel(
    const float* __restrict__ eps, const float* __restrict__ mu,
    const float* __restrict__ lv, float* __restrict__ slots)
{
    int idx = blockIdx.x * blockDim.x + threadIdx.x;   // 65536 exact
    int d = idx & 63;
    slots[idx] = mu[d] + __expf(0.5f * lv[d]) * eps[idx];
}

// ---------------- phase A: LN + k/v projections via MFMA, bf16 out ----------------
// Block = 256 thr (4 waves) handles 128 tokens. C[128 tok][128 out] = X_ln @ Wcat^T.
// LDS rows padded to 72 bf16 (144 B) => stride 36 banks => 2-way conflict (free).
__global__ __launch_bounds__(256) void phase_a_mfma(
    const float* __restrict__ inp, const unsigned short* __restrict__ wcat,
    const float* __restrict__ niw, const float* __restrict__ nib,
    __hip_bfloat16* __restrict__ kb, __hip_bfloat16* __restrict__ vb)
{
    __shared__ short Xs[128 * 72];
    __shared__ short Ws[128 * 72];
    const int tid = threadIdx.x, lane = tid & 63, widx = tid >> 6;

    // stage weights (bf16 pairs as uint)
    {
        const unsigned* wg = (const unsigned*)wcat;
        #pragma unroll 4
        for (int t = tid; t < 4096; t += 256) {
            int n = t >> 5, kp = t & 31;
            *(unsigned*)&Ws[n * 72 + kp * 2] = wg[t];
        }
    }

    const float w_ni = niw[lane], b_ni = nib[lane];
    const int tok0 = blockIdx.x * 128;
    // LN: each wave 32 tokens, lane = feature
    for (int it = 0; it < 32; ++it) {
        const int m = widx * 32 + it;
        float x = inp[(size_t)(tok0 + m) * 64 + lane];
        float mean = warp_red_sum(x) * (1.0f / 64.0f);
        float dx = x - mean;
        float var = warp_red_sum(dx * dx) * (1.0f / 64.0f);
        float xln = dx * rsqrtf(var + 1e-5f) * w_ni + b_ni;
        __hip_bfloat16 h = __float2bfloat16(xln);
        Xs[m * 72 + lane] = *(short*)&h;
    }
    __syncthreads();

    const int quad = lane >> 4, l16 = lane & 15;
    // wave widx: M-tiles {2*widx, 2*widx+1}, all 8 N-tiles, K = 2 steps of 32
    short8 afr[2][2];
    #pragma unroll
    for (int mt = 0; mt < 2; ++mt)
        #pragma unroll
        for (int ks = 0; ks < 2; ++ks)
            afr[mt][ks] = *(const short8*)&Xs[(widx * 32 + mt * 16 + l16) * 72 + ks * 32 + quad * 8];

    f32x4 acc[2][8];
    #pragma unroll
    for (int mt = 0; mt < 2; ++mt)
        #pragma unroll
        for (int nt = 0; nt < 8; ++nt)
            acc[mt][nt] = (f32x4){0.f, 0.f, 0.f, 0.f};

    #pragma unroll
    for (int nt = 0; nt < 8; ++nt) {
        #pragma unroll
        for (int ks = 0; ks < 2; ++ks) {
            short8 bfr = *(const short8*)&Ws[(nt * 16 + l16) * 72 + ks * 32 + quad * 8];
            acc[0][nt] = __builtin_amdgcn_mfma_f32_16x16x32_bf16(afr[0][ks], bfr, acc[0][nt], 0, 0, 0);
            acc[1][nt] = __builtin_amdgcn_mfma_f32_16x16x32_bf16(afr[1][ks], bfr, acc[1][nt], 0, 0, 0);
        }
    }

    // epilogue: D layout col=lane&15, row=quad*4+r
    #pragma unroll
    for (int mt = 0; mt < 2; ++mt) {
        #pragma unroll
        for (int nt = 0; nt < 8; ++nt) {
            #pragma unroll
            for (int r = 0; r < 4; ++r) {
                const int tok = tok0 + widx * 32 + mt * 16 + quad * 4 + r;
                const int col = nt * 16 + l16;
                __hip_bfloat16 h = __float2bfloat16(acc[mt][nt][r]);
                if (nt < 4) kb[(size_t)tok * 64 + col] = h;
                else        vb[(size_t)tok * 64 + (col - 64)] = h;
            }
        }
    }
}

// ---------------- q = LN(slots) @ q_w.T ----------------
__global__ __launch_bounds__(256) void q_kernel(
    const float* __restrict__ slots, const float* __restrict__ qwT,
    const float* __restrict__ nsw, const float* __restrict__ nsb, float* __restrict__ qout)
{
    const int lane = threadIdx.x & 63;
    const int row = blockIdx.x * 4 + (threadIdx.x >> 6);   // grid 256 -> 1024 rows
    float x = slots[row * 64 + lane];
    float m = warp_red_sum(x) * (1.0f / 64.0f);
    float dx = x - m;
    float var = warp_red_sum(dx * dx) * (1.0f / 64.0f);
    float xln = dx * rsqrtf(var + 1e-5f) * nsw[lane] + nsb[lane];
    float acc = 0.f;
    #pragma unroll 16
    for (int i = 0; i < 64; ++i) acc = fmaf(bcastlane(xln, i), qwT[i * 64 + lane], acc);
    qout[row * 64 + lane] = acc;
}

// ---------------- attention: logits -> softmax+EPS -> accumulate numer/denom ----------------
__global__ __launch_bounds__(256) void attn_kernel(
    const __hip_bfloat16* __restrict__ kb, const __hip_bfloat16* __restrict__ vb,
    const float* __restrict__ qbuf, float* __restrict__ numer, float* __restrict__ denom,
    float* __restrict__ wout)
{
    __shared__ float q_lds[512];
    __shared__ float red[2048];
    __shared__ float dred[32];
    const int tid = threadIdx.x, lane = tid & 63, widx = tid >> 6;
    const int b = blockIdx.y, chunk = blockIdx.x;      // grid (8,128): 512 tokens per block
    for (int t = tid; t < 512; t += 256) q_lds[t] = qbuf[b * 512 + t];
    __syncthreads();

    float nm[8], dsum[8];
    #pragma unroll
    for (int s = 0; s < 8; ++s) { nm[s] = 0.f; dsum[s] = 0.f; }

    #pragma unroll 1
    for (int itr = 0; itr < 2; ++itr) {
        const int gbase = chunk * 512 + itr * 256 + widx * 64;
        const int tok = gbase + lane;
        float kr[64];
        const uint4* kp = reinterpret_cast<const uint4*>(kb + ((size_t)b * NN + tok) * 64);
        #pragma unroll
        for (int c = 0; c < 8; ++c) {
            uint4 u = kp[c];
            unp2(u.x, kr[c * 8 + 0], kr[c * 8 + 1]);
            unp2(u.y, kr[c * 8 + 2], kr[c * 8 + 3]);
            unp2(u.z, kr[c * 8 + 4], kr[c * 8 + 5]);
            unp2(u.w, kr[c * 8 + 6], kr[c * 8 + 7]);
        }
        float wv[8];
        #pragma unroll
        for (int s = 0; s < 8; ++s) {
            float acc = 0.f;
            #pragma unroll
            for (int i = 0; i < 64; ++i) acc = fmaf(kr[i], q_lds[s * 64 + i], acc);
            wv[s] = acc;
        }
        float mx = wv[0];
        #pragma unroll
        for (int s = 1; s < 8; ++s) mx = fmaxf(mx, wv[s]);
        float sum = 0.f;
        #pragma unroll
        for (int s = 0; s < 8; ++s) { wv[s] = __expf(wv[s] - mx); sum += wv[s]; }
        float rs = 1.0f / sum;
        #pragma unroll
        for (int s = 0; s < 8; ++s) { wv[s] = fmaf(wv[s], rs, 1e-8f); dsum[s] += wv[s]; }
        if (wout) {
            float4* wp = reinterpret_cast<float4*>(wout + ((size_t)b * NN + tok) * 8);
            wp[0] = make_float4(wv[0], wv[1], wv[2], wv[3]);
            wp[1] = make_float4(wv[4], wv[5], wv[6], wv[7]);
        }
        const __hip_bfloat16* vbase = vb + ((size_t)b * NN + gbase) * 64;
        #pragma unroll 8
        for (int t2 = 0; t2 < 64; ++t2) {
            float vv = __bfloat162float(vbase[t2 * 64 + lane]);
            #pragma unroll
            for (int s = 0; s < 8; ++s) nm[s] = fmaf(bcastlane(wv[s], t2), vv, nm[s]);
        }
    }

    #pragma unroll
    for (int s = 0; s < 8; ++s) red[widx * 512 + s * 64 + lane] = nm[s];
    #pragma unroll
    for (int s = 0; s < 8; ++s) dsum[s] = warp_red_sum(dsum[s]);
    if (lane == 0) {
        #pragma unroll
        for (int s = 0; s < 8; ++s) dred[widx * 8 + s] = dsum[s];
    }
    __syncthreads();
    for (int e = tid; e < 512; e += 256) {
        float v = red[e] + red[512 + e] + red[1024 + e] + red[1536 + e];
        atomicAdd(numer + (size_t)b * 512 + e, v);
    }
    if (tid < 8) atomicAdd(denom + b * 8 + tid,
                           dred[tid] + dred[8 + tid] + dred[16 + tid] + dred[24 + tid]);
}

// ---------------- GRU + MLP per slot row ----------------
__global__ __launch_bounds__(256) void gru_kernel(
    const float* __restrict__ numer, const float* __restrict__ denom,
    const float* __restrict__ slotsIn,
    const float* __restrict__ wihT, const float* __restrict__ whhT,
    const float* __restrict__ w1T, const float* __restrict__ w2T,
    const float* __restrict__ bih, const float* __restrict__ bhh,
    const float* __restrict__ nrw, const float* __restrict__ nrb,
    const float* __restrict__ b2, float* __restrict__ slotsOut)
{
    const int lane = threadIdx.x & 63;
    const int row = blockIdx.x * 4 + (threadIdx.x >> 6);   // grid 256 -> 1024 rows
    float x = numer[row * 64 + lane] / denom[row];
    float h = slotsIn[row * 64 + lane];
    float air = 0, aiz = 0, ain = 0, ahr = 0, ahz = 0, ahn = 0;
    #pragma unroll 8
    for (int i = 0; i < 64; ++i) {
        float xi = bcastlane(x, i), hi = bcastlane(h, i);
        const float* wi = wihT + i * 192;
        const float* wh = whhT + i * 192;
        air = fmaf(xi, wi[lane], air);
        aiz = fmaf(xi, wi[64 + lane], aiz);
        ain = fmaf(xi, wi[128 + lane], ain);
        ahr = fmaf(hi, wh[lane], ahr);
        ahz = fmaf(hi, wh[64 + lane], ahz);
        ahn = fmaf(hi, wh[128 + lane], ahn);
    }
    air += bih[lane]; aiz += bih[64 + lane]; ain += bih[128 + lane];
    ahr += bhh[lane]; ahz += bhh[64 + lane]; ahn += bhh[128 + lane];
    float r = 1.f / (1.f + __expf(-(air + ahr)));
    float z = 1.f / (1.f + __expf(-(aiz + ahz)));
    float n = tanhf(ain + r * ahn);
    float hn = (1.f - z) * n + z * h;
    float m = warp_red_sum(hn) * (1.0f / 64.0f);
    float dx = hn - m;
    float var = warp_red_sum(dx * dx) * (1.0f / 64.0f);
    float u = dx * rsqrtf(var + 1e-5f) * nrw[lane] + nrb[lane];
    float o0 = 0.f, o1 = 0.f;
    #pragma unroll 8
    for (int i = 0; i < 64; ++i) {
        float ui = bcastlane(u, i);
        const float* w1r = w1T + i * 128;
        o0 = fmaf(ui, w1r[lane], o0);
        o1 = fmaf(ui, w1r[64 + lane], o1);
    }
    o0 = fmaxf(o0, 0.f); o1 = fmaxf(o1, 0.f);
    float y = 0.f;
    #pragma unroll 8
    for (int j = 0; j < 64; ++j) y = fmaf(bcastlane(o0, j), w2T[j * 64 + lane], y);
    #pragma unroll 8
    for (int j = 0; j < 64; ++j) y = fmaf(bcastlane(o1, j), w2T[(64 + j) * 64 + lane], y);
    y += b2[lane];
    slotsOut[row * 64 + lane] = hn + y;
}

// ---------------- final renorm of w output ----------------
__global__ __launch_bounds__(256) void renorm_kernel(float* __restrict__ wout,
                                                     const float* __restrict__ denom)
{
    const size_t i4 = (size_t)blockIdx.x * blockDim.x + threadIdx.x;  // 1,048,576 float4s
    const size_t b = i4 >> 13;
    const int half = (int)(i4 & 1);
    float4 v = reinterpret_cast<float4*>(wout)[i4];
    const float4 dv = reinterpret_cast<const float4*>(denom)[b * 2 + half];
    v.x /= dv.x; v.y /= dv.y; v.z /= dv.z; v.w /= dv.w;
    reinterpret_cast<float4*>(wout)[i4] = v;
}

extern "C" void kernel_launch(void* const* d_in, const int* in_sizes, int n_in,
                              void* d_out, int out_size, void* d_ws, size_t ws_size,
                              hipStream_t stream)
{
    const float* inputs  = (const float*)d_in[0];
    const float* eps_n   = (const float*)d_in[1];
    const float* mu      = (const float*)d_in[2];
    const float* lv      = (const float*)d_in[3];
    const float* k_w     = (const float*)d_in[4];
    const float* v_w     = (const float*)d_in[5];
    const float* q_w     = (const float*)d_in[6];
    const float* ni_w    = (const float*)d_in[7];
    const float* ni_b    = (const float*)d_in[8];
    const float* ns_w    = (const float*)d_in[9];
    const float* ns_b    = (const float*)d_in[10];
    const float* nr_w    = (const float*)d_in[11];
    const float* nr_b    = (const float*)d_in[12];
    const float* gru_wih = (const float*)d_in[13];
    const float* gru_whh = (const float*)d_in[14];
    const float* gru_bih = (const float*)d_in[15];
    const float* gru_bhh = (const float*)d_in[16];
    const float* mlp_w1  = (const float*)d_in[17];
    const float* mlp_w2  = (const float*)d_in[18];
    const float* mlp_b2  = (const float*)d_in[19];

    char* wsb = (char*)d_ws;
    __hip_bfloat16* kb = (__hip_bfloat16*)wsb;                       // 67,108,864 B
    __hip_bfloat16* vb = (__hip_bfloat16*)(wsb + 67108864);          // 67,108,864 B
    float* f      = (float*)(wsb + 134217728);
    float* slotsA = f;                  // 65536
    float* slotsB = f + 65536;          // 65536
    float* qbuf   = f + 131072;         // 65536
    float* numer  = f + 196608;         // 65536
    float* denom  = f + 262144;         // 1024
    unsigned short* wcat = (unsigned short*)(f + 263168);  // 8192 bf16 = 16 KB
    float* qwT    = f + 263168 + 4096;  // 4096
    float* wihT   = qwT + 4096;         // 12288
    float* whhT   = wihT + 12288;       // 12288
    float* w1T    = whhT + 12288;       // 8192
    float* w2T    = w1T + 8192;         // 8192

    float* out_slots = (float*)d_out;
    float* out_w     = out_slots + 65536;

    prep_kernel<<<64, 256, 0, stream>>>(k_w, v_w, q_w, gru_wih, gru_whh, mlp_w1, mlp_w2,
                                        wcat, qwT, wihT, whhT, w1T, w2T);
    slots_init_kernel<<<256, 256, 0, stream>>>(eps_n, mu, lv, slotsA);
    phase_a_mfma<<<4096, 256, 0, stream>>>(inputs, wcat, ni_w, ni_b, kb, vb);

    float* cur = slotsA;
    for (int step = 0; step < 4; ++step) {
        hipMemsetAsync(numer, 0, (65536 + 1024) * sizeof(float), stream);
        q_kernel<<<256, 256, 0, stream>>>(cur, qwT, ns_w, ns_b, qbuf);
        attn_kernel<<<dim3(8, 128), 256, 0, stream>>>(kb, vb, qbuf, numer, denom,
                                                      step == 3 ? out_w : nullptr);
        float* nxt = (step == 3) ? out_slots : ((step & 1) ? slotsA : slotsB);
        gru_kernel<<<256, 256, 0, stream>>>(numer, denom, cur, wihT, whhT, w1T, w2T,
                                            gru_bih, gru_bhh, nr_w, nr_b, mlp_b2, nxt);
        cur = nxt;
    }
    renorm_kernel<<<4096, 256, 0, stream>>>(out_w, denom);
}

// Round 3
// 494.561 us; speedup vs baseline: 3.0606x; 2.5375x over previous
//
#include <hip/hip_runtime.h>
#include <hip/hip_bf16.h>

#define BB 128
#define NN 4096
#define DD 64
#define SS 8
#define HH 128

typedef __attribute__((ext_vector_type(8))) short short8;
typedef __attribute__((ext_vector_type(4))) float f32x4;

__device__ __forceinline__ float warp_red_sum(float v) {
    #pragma unroll
    for (int off = 32; off; off >>= 1) v += __shfl_xor(v, off);
    return v;
}

__device__ __forceinline__ float bcastlane(float v, int l) {
    return __int_as_float(__builtin_amdgcn_readlane(__float_as_int(v), l));
}

__device__ __forceinline__ unsigned short bfu(float f) {
    __hip_bfloat16 h = __float2bfloat16(f);
    return *(unsigned short*)&h;
}

// ---------------- prep: weight transposes + bf16 [kw*0.125 ; vw] cat ----------------
__global__ __launch_bounds__(256) void prep_kernel(
    const float* __restrict__ k_w, const float* __restrict__ v_w, const float* __restrict__ q_w,
    const float* __restrict__ wih, const float* __restrict__ whh,
    const float* __restrict__ w1, const float* __restrict__ w2,
    unsigned short* __restrict__ wcat, float* __restrict__ qwT,
    float* __restrict__ wihT, float* __restrict__ whhT,
    float* __restrict__ w1T, float* __restrict__ w2T)
{
    int i0 = blockIdx.x * blockDim.x + threadIdx.x;
    int nthr = gridDim.x * blockDim.x;
    for (int t = i0; t < 8192; t += nthr) {
        int n = t >> 6, k = t & 63;
        float val = (n < 64) ? k_w[n * 64 + k] * 0.125f : v_w[(n - 64) * 64 + k];
        wcat[t] = bfu(val);
    }
    for (int t = i0; t < 4096; t += nthr) {
        int r = t >> 6, c = t & 63;
        qwT[t] = q_w[c * 64 + r];
    }
    for (int t = i0; t < 12288; t += nthr) {
        int r = t / 192, c = t % 192;
        wihT[t] = wih[c * 64 + r];
        whhT[t] = whh[c * 64 + r];
    }
    for (int t = i0; t < 8192; t += nthr) {
        int r = t >> 7, c = t & 127;
        w1T[t] = w1[c * 64 + r];
    }
    for (int t = i0; t < 8192; t += nthr) {
        int r = t >> 6, c = t & 63;
        w2T[t] = w2[c * 128 + r];
    }
}

// ---------------- slots init ----------------
__global__ __launch_bounds__(256) void slots_init_kernel(
    const float* __restrict__ eps, const float* __restrict__ mu,
    const float* __restrict__ lv, float* __restrict__ slots)
{
    int idx = blockIdx.x * blockDim.x + threadIdx.x;
    int d = idx & 63;
    slots[idx] = mu[d] + __expf(0.5f * lv[d]) * eps[idx];
}

// ---------------- phase A: LN + k/v proj via MFMA; k -> [tok][d], v -> TRANSPOSED [b][d][tok] ----------------
__global__ __launch_bounds__(256) void phase_a_mfma(
    const float* __restrict__ inp, const unsigned short* __restrict__ wcat,
    const float* __restrict__ niw, const float* __restrict__ nib,
    __hip_bfloat16* __restrict__ kb, unsigned short* __restrict__ vbt)
{
    __shared__ short smemA[18432];           // 36,864 B
    short* Xs = smemA;                       // [128][72]
    short* Ws = smemA + 9216;                // [128][72]
    float* vtf = (float*)smemA;              // reuse: [64][132] floats = 33,792 B
    const int tid = threadIdx.x, lane = tid & 63, widx = tid >> 6;

    {
        const unsigned* wg = (const unsigned*)wcat;
        #pragma unroll 4
        for (int t = tid; t < 4096; t += 256) {
            int n = t >> 5, kp = t & 31;
            *(unsigned*)&Ws[n * 72 + kp * 2] = wg[t];
        }
    }

    const float w_ni = niw[lane], b_ni = nib[lane];
    const int tok0 = blockIdx.x * 128;
    for (int it = 0; it < 32; ++it) {
        const int m = widx * 32 + it;
        float x = inp[(size_t)(tok0 + m) * 64 + lane];
        float mean = warp_red_sum(x) * (1.0f / 64.0f);
        float dx = x - mean;
        float var = warp_red_sum(dx * dx) * (1.0f / 64.0f);
        float xln = dx * rsqrtf(var + 1e-5f) * w_ni + b_ni;
        Xs[m * 72 + lane] = (short)bfu(xln);
    }
    __syncthreads();

    const int quad = lane >> 4, l16 = lane & 15;
    short8 afr[2][2];
    #pragma unroll
    for (int mt = 0; mt < 2; ++mt)
        #pragma unroll
        for (int ks = 0; ks < 2; ++ks)
            afr[mt][ks] = *(const short8*)&Xs[(widx * 32 + mt * 16 + l16) * 72 + ks * 32 + quad * 8];

    f32x4 acc[2][8];
    #pragma unroll
    for (int mt = 0; mt < 2; ++mt)
        #pragma unroll
        for (int nt = 0; nt < 8; ++nt)
            acc[mt][nt] = (f32x4){0.f, 0.f, 0.f, 0.f};

    #pragma unroll
    for (int nt = 0; nt < 8; ++nt) {
        #pragma unroll
        for (int ks = 0; ks < 2; ++ks) {
            short8 bfr = *(const short8*)&Ws[(nt * 16 + l16) * 72 + ks * 32 + quad * 8];
            acc[0][nt] = __builtin_amdgcn_mfma_f32_16x16x32_bf16(afr[0][ks], bfr, acc[0][nt], 0, 0, 0);
            acc[1][nt] = __builtin_amdgcn_mfma_f32_16x16x32_bf16(afr[1][ks], bfr, acc[1][nt], 0, 0, 0);
        }
    }

    // k epilogue: direct coalesced-ish scalar bf16 stores (as R1, passed)
    #pragma unroll
    for (int mt = 0; mt < 2; ++mt) {
        #pragma unroll
        for (int nt = 0; nt < 4; ++nt) {
            #pragma unroll
            for (int r = 0; r < 4; ++r) {
                const int tok = tok0 + widx * 32 + mt * 16 + quad * 4 + r;
                const int col = nt * 16 + l16;
                __hip_bfloat16 h = __float2bfloat16(acc[mt][nt][r]);
                kb[(size_t)tok * 64 + col] = h;
            }
        }
    }
    // v epilogue: LDS transpose -> vbt[b][d][tok]
    __syncthreads();   // all Xs/Ws reads done; safe to overwrite as vtf
    #pragma unroll
    for (int mt = 0; mt < 2; ++mt) {
        #pragma unroll
        for (int nt = 4; nt < 8; ++nt) {
            #pragma unroll
            for (int r = 0; r < 4; ++r) {
                const int d = (nt - 4) * 16 + l16;
                const int tl = widx * 32 + mt * 16 + quad * 4 + r;
                vtf[d * 132 + tl] = acc[mt][nt][r];
            }
        }
    }
    __syncthreads();
    const int b = blockIdx.x >> 5, tin = (blockIdx.x & 31) * 128;
    const int d = tid >> 2, c0 = (tid & 3) * 32;
    #pragma unroll
    for (int c = 0; c < 4; ++c) {
        float4 f0 = *(float4*)&vtf[d * 132 + c0 + c * 8];
        float4 f1 = *(float4*)&vtf[d * 132 + c0 + c * 8 + 4];
        uint4 o;
        o.x = (unsigned)bfu(f0.x) | ((unsigned)bfu(f0.y) << 16);
        o.y = (unsigned)bfu(f0.z) | ((unsigned)bfu(f0.w) << 16);
        o.z = (unsigned)bfu(f1.x) | ((unsigned)bfu(f1.y) << 16);
        o.w = (unsigned)bfu(f1.z) | ((unsigned)bfu(f1.w) << 16);
        *(uint4*)&vbt[((size_t)b * 64 + d) * 4096 + tin + c0 + c * 8] = o;
    }
}

// ---------------- q = LN(slots) @ q_w.T -> bf16 ----------------
__global__ __launch_bounds__(256) void q_kernel(
    const float* __restrict__ slots, const float* __restrict__ qwT,
    const float* __restrict__ nsw, const float* __restrict__ nsb,
    unsigned short* __restrict__ qout)
{
    const int lane = threadIdx.x & 63;
    const int row = blockIdx.x * 4 + (threadIdx.x >> 6);
    float x = slots[row * 64 + lane];
    float m = warp_red_sum(x) * (1.0f / 64.0f);
    float dx = x - m;
    float var = warp_red_sum(dx * dx) * (1.0f / 64.0f);
    float xln = dx * rsqrtf(var + 1e-5f) * nsw[lane] + nsb[lane];
    float acc = 0.f;
    #pragma unroll 16
    for (int i = 0; i < 64; ++i) acc = fmaf(bcastlane(xln, i), qwT[i * 64 + lane], acc);
    qout[row * 64 + lane] = bfu(acc);
}

// ---------------- attention via MFMA: QK^T -> softmax -> w^T @ v ----------------
// grid (8, 128): 8 blocks/batch, 512 tok/block, 128 tok/wave (2 iters of 64).
// LDS: Qs [16][72] + per-wave wls [16][72] + per-wave vt [64][72] = 48,384 B -> 3 blocks/CU.
__global__ __launch_bounds__(256) void attn_mfma(
    const __hip_bfloat16* __restrict__ kb, const unsigned short* __restrict__ vbt,
    const unsigned short* __restrict__ qb,
    float* __restrict__ numer, float* __restrict__ denom, float* __restrict__ wout)
{
    __shared__ unsigned short smem[24192];
    unsigned short* Qs = smem;                          // [16][72]
    const int tid = threadIdx.x, lane = tid & 63, widx = tid >> 6;
    unsigned short* wls = smem + 1152 + widx * 1152;    // [16][72]
    unsigned short* vt  = smem + 5760 + widx * 4608;    // [64][72]
    const int b = blockIdx.y;

    for (int t = tid; t < 1024; t += 256) {
        int s = t >> 6, dd = t & 63;
        Qs[s * 72 + dd] = (s < 8) ? qb[b * 512 + t] : (unsigned short)0;
    }
    for (int t = lane; t < 576; t += 64) wls[576 + t] = 0;   // zero slot-pad rows 8..15
    __syncthreads();

    const int quad = lane >> 4, l16 = lane & 15;
    short8 bq0 = *(const short8*)&Qs[l16 * 72 + quad * 8];
    short8 bq1 = *(const short8*)&Qs[l16 * 72 + 32 + quad * 8];

    f32x4 accv[4];
    #pragma unroll
    for (int nt = 0; nt < 4; ++nt) accv[nt] = (f32x4){0.f, 0.f, 0.f, 0.f};
    float dsum = 0.f;

    const int twave0 = blockIdx.x * 512 + widx * 128;
    const int vd = lane >> 3, vc = (lane & 7) * 8;
    #pragma unroll
    for (int iter = 0; iter < 2; ++iter) {
        const int t0 = twave0 + iter * 64;
        // stage v^T tile (64 d x 64 tok), per-wave, issued early
        uint4 vld[8];
        #pragma unroll
        for (int i = 0; i < 8; ++i)
            vld[i] = *(const uint4*)&vbt[((size_t)b * 64 + i * 8 + vd) * 4096 + t0 + vc];

        // QK^T + softmax per 16-token tile
        #pragma unroll
        for (int t4 = 0; t4 < 4; ++t4) {
            const size_t krow = ((size_t)b * NN + t0 + t4 * 16 + l16) * 64;
            short8 ak0 = *(const short8*)&kb[krow + quad * 8];
            short8 ak1 = *(const short8*)&kb[krow + 32 + quad * 8];
            f32x4 lg = (f32x4){0.f, 0.f, 0.f, 0.f};
            lg = __builtin_amdgcn_mfma_f32_16x16x32_bf16(ak0, bq0, lg, 0, 0, 0);
            lg = __builtin_amdgcn_mfma_f32_16x16x32_bf16(ak1, bq1, lg, 0, 0, 0);
            // lane holds logits for tok = t0+t4*16+quad*4+r, s = l16 (s>=8 invalid)
            float wv[4];
            #pragma unroll
            for (int r = 0; r < 4; ++r) {
                float e = __expf(lg[r]);         // no max-sub: |logit| ~ O(10), fp32-safe
                float s = e;
                s += __shfl_xor(s, 1); s += __shfl_xor(s, 2); s += __shfl_xor(s, 4);
                wv[r] = e / s + 1e-8f;
                dsum += wv[r];
            }
            if (l16 < 8) {
                unsigned p01 = (unsigned)bfu(wv[0]) | ((unsigned)bfu(wv[1]) << 16);
                unsigned p23 = (unsigned)bfu(wv[2]) | ((unsigned)bfu(wv[3]) << 16);
                *(unsigned*)&wls[l16 * 72 + t4 * 16 + quad * 4]     = p01;
                *(unsigned*)&wls[l16 * 72 + t4 * 16 + quad * 4 + 2] = p23;
                if (wout) {
                    float* wp = wout + ((size_t)b * NN + t0 + t4 * 16 + quad * 4) * 8 + l16;
                    wp[0] = wv[0]; wp[8] = wv[1]; wp[16] = wv[2]; wp[24] = wv[3];
                }
            }
        }
        // commit v^T tile to LDS
        #pragma unroll
        for (int i = 0; i < 8; ++i)
            *(uint4*)&vt[(i * 8 + vd) * 72 + vc] = vld[i];
        // PV: numer[s][d] += w^T @ v  (K = 64 tokens, 2 steps)
        #pragma unroll
        for (int ks = 0; ks < 2; ++ks) {
            short8 aw = *(const short8*)&wls[l16 * 72 + ks * 32 + quad * 8];
            #pragma unroll
            for (int nt = 0; nt < 4; ++nt) {
                short8 bv = *(const short8*)&vt[(nt * 16 + l16) * 72 + ks * 32 + quad * 8];
                accv[nt] = __builtin_amdgcn_mfma_f32_16x16x32_bf16(aw, bv, accv[nt], 0, 0, 0);
            }
        }
    }
    // reduce across waves + atomics
    dsum += __shfl_xor(dsum, 16);
    dsum += __shfl_xor(dsum, 32);
    __syncthreads();
    float* red = (float*)(smem + 5760);    // 2048 floats over vt region
    float* dred = red + 2048;
    if (quad < 2) {
        #pragma unroll
        for (int nt = 0; nt < 4; ++nt)
            #pragma unroll
            for (int r = 0; r < 4; ++r)
                red[widx * 512 + (quad * 4 + r) * 64 + nt * 16 + l16] = accv[nt][r];
    }
    if (quad == 0 && l16 < 8) dred[widx * 8 + l16] = dsum;
    __syncthreads();
    for (int e = tid; e < 512; e += 256)
        atomicAdd(numer + (size_t)b * 512 + e, red[e] + red[512 + e] + red[1024 + e] + red[1536 + e]);
    if (tid < 8)
        atomicAdd(denom + b * 8 + tid, dred[tid] + dred[8 + tid] + dred[16 + tid] + dred[24 + tid]);
}

// ---------------- GRU + MLP per slot row ----------------
__global__ __launch_bounds__(256) void gru_kernel(
    const float* __restrict__ numer, const float* __restrict__ denom,
    const float* __restrict__ slotsIn,
    const float* __restrict__ wihT, const float* __restrict__ whhT,
    const float* __restrict__ w1T, const float* __restrict__ w2T,
    const float* __restrict__ bih, const float* __restrict__ bhh,
    const float* __restrict__ nrw, const float* __restrict__ nrb,
    const float* __restrict__ b2, float* __restrict__ slotsOut)
{
    const int lane = threadIdx.x & 63;
    const int row = blockIdx.x * 4 + (threadIdx.x >> 6);
    float x = numer[row * 64 + lane] / denom[row];
    float h = slotsIn[row * 64 + lane];
    float air = 0, aiz = 0, ain = 0, ahr = 0, ahz = 0, ahn = 0;
    #pragma unroll 8
    for (int i = 0; i < 64; ++i) {
        float xi = bcastlane(x, i), hi = bcastlane(h, i);
        const float* wi = wihT + i * 192;
        const float* wh = whhT + i * 192;
        air = fmaf(xi, wi[lane], air);
        aiz = fmaf(xi, wi[64 + lane], aiz);
        ain = fmaf(xi, wi[128 + lane], ain);
        ahr = fmaf(hi, wh[lane], ahr);
        ahz = fmaf(hi, wh[64 + lane], ahz);
        ahn = fmaf(hi, wh[128 + lane], ahn);
    }
    air += bih[lane]; aiz += bih[64 + lane]; ain += bih[128 + lane];
    ahr += bhh[lane]; ahz += bhh[64 + lane]; ahn += bhh[128 + lane];
    float r = 1.f / (1.f + __expf(-(air + ahr)));
    float z = 1.f / (1.f + __expf(-(aiz + ahz)));
    float n = tanhf(ain + r * ahn);
    float hn = (1.f - z) * n + z * h;
    float m = warp_red_sum(hn) * (1.0f / 64.0f);
    float dx = hn - m;
    float var = warp_red_sum(dx * dx) * (1.0f / 64.0f);
    float u = dx * rsqrtf(var + 1e-5f) * nrw[lane] + nrb[lane];
    float o0 = 0.f, o1 = 0.f;
    #pragma unroll 8
    for (int i = 0; i < 64; ++i) {
        float ui = bcastlane(u, i);
        const float* w1r = w1T + i * 128;
        o0 = fmaf(ui, w1r[lane], o0);
        o1 = fmaf(ui, w1r[64 + lane], o1);
    }
    o0 = fmaxf(o0, 0.f); o1 = fmaxf(o1, 0.f);
    float y = 0.f;
    #pragma unroll 8
    for (int j = 0; j < 64; ++j) y = fmaf(bcastlane(o0, j), w2T[j * 64 + lane], y);
    #pragma unroll 8
    for (int j = 0; j < 64; ++j) y = fmaf(bcastlane(o1, j), w2T[(64 + j) * 64 + lane], y);
    y += b2[lane];
    slotsOut[row * 64 + lane] = hn + y;
}

// ---------------- final renorm of w output ----------------
__global__ __launch_bounds__(256) void renorm_kernel(float* __restrict__ wout,
                                                     const float* __restrict__ denom)
{
    const size_t i4 = (size_t)blockIdx.x * blockDim.x + threadIdx.x;
    const size_t b = i4 >> 13;
    const int half = (int)(i4 & 1);
    float4 v = reinterpret_cast<float4*>(wout)[i4];
    const float4 dv = reinterpret_cast<const float4*>(denom)[b * 2 + half];
    v.x /= dv.x; v.y /= dv.y; v.z /= dv.z; v.w /= dv.w;
    reinterpret_cast<float4*>(wout)[i4] = v;
}

extern "C" void kernel_launch(void* const* d_in, const int* in_sizes, int n_in,
                              void* d_out, int out_size, void* d_ws, size_t ws_size,
                              hipStream_t stream)
{
    const float* inputs  = (const float*)d_in[0];
    const float* eps_n   = (const float*)d_in[1];
    const float* mu      = (const float*)d_in[2];
    const float* lv      = (const float*)d_in[3];
    const float* k_w     = (const float*)d_in[4];
    const float* v_w     = (const float*)d_in[5];
    const float* q_w     = (const float*)d_in[6];
    const float* ni_w    = (const float*)d_in[7];
    const float* ni_b    = (const float*)d_in[8];
    const float* ns_w    = (const float*)d_in[9];
    const float* ns_b    = (const float*)d_in[10];
    const float* nr_w    = (const float*)d_in[11];
    const float* nr_b    = (const float*)d_in[12];
    const float* gru_wih = (const float*)d_in[13];
    const float* gru_whh = (const float*)d_in[14];
    const float* gru_bih = (const float*)d_in[15];
    const float* gru_bhh = (const float*)d_in[16];
    const float* mlp_w1  = (const float*)d_in[17];
    const float* mlp_w2  = (const float*)d_in[18];
    const float* mlp_b2  = (const float*)d_in[19];

    char* wsb = (char*)d_ws;
    __hip_bfloat16* kb  = (__hip_bfloat16*)wsb;                    // [B][N][64] bf16
    unsigned short* vbt = (unsigned short*)(wsb + 67108864);       // [B][64][N] bf16 (transposed)
    float* f      = (float*)(wsb + 134217728);
    float* slotsA = f;                  // 65536
    float* slotsB = f + 65536;          // 65536
    unsigned short* qb = (unsigned short*)(f + 131072);  // [B][8][64] bf16
    float* numer  = f + 196608;         // 65536
    float* denom  = f + 262144;         // 1024
    unsigned short* wcat = (unsigned short*)(f + 263168);  // 8192 bf16
    float* qwT    = f + 263168 + 4096;  // 4096
    float* wihT   = qwT + 4096;
    float* whhT   = wihT + 12288;
    float* w1T    = whhT + 12288;
    float* w2T    = w1T + 8192;

    float* out_slots = (float*)d_out;
    float* out_w     = out_slots + 65536;

    prep_kernel<<<64, 256, 0, stream>>>(k_w, v_w, q_w, gru_wih, gru_whh, mlp_w1, mlp_w2,
                                        wcat, qwT, wihT, whhT, w1T, w2T);
    slots_init_kernel<<<256, 256, 0, stream>>>(eps_n, mu, lv, slotsA);
    phase_a_mfma<<<4096, 256, 0, stream>>>(inputs, wcat, ni_w, ni_b, kb, vbt);

    float* cur = slotsA;
    for (int step = 0; step < 4; ++step) {
        hipMemsetAsync(numer, 0, (65536 + 1024) * sizeof(float), stream);
        q_kernel<<<256, 256, 0, stream>>>(cur, qwT, ns_w, ns_b, qb);
        attn_mfma<<<dim3(8, 128), 256, 0, stream>>>(kb, vbt, qb, numer, denom,
                                                    step == 3 ? out_w : nullptr);
        float* nxt = (step == 3) ? out_slots : ((step & 1) ? slotsA : slotsB);
        gru_kernel<<<256, 256, 0, stream>>>(numer, denom, cur, wihT, whhT, w1T, w2T,
                                            gru_bih, gru_bhh, nr_w, nr_b, mlp_b2, nxt);
        cur = nxt;
    }
    renorm_kernel<<<4096, 256, 0, stream>>>(out_w, denom);
}

// Round 4
// 451.379 us; speedup vs baseline: 3.3534x; 1.0957x over previous
//
#include <hip/hip_runtime.h>
#include <hip/hip_bf16.h>

#define BB 128
#define NN 4096
#define DD 64
#define SS 8
#define HH 128

typedef __attribute__((ext_vector_type(8))) short short8;
typedef __attribute__((ext_vector_type(4))) float f32x4;

__device__ __forceinline__ float warp_red_sum(float v) {
    #pragma unroll
    for (int off = 32; off; off >>= 1) v += __shfl_xor(v, off);
    return v;
}

__device__ __forceinline__ float bcastlane(float v, int l) {
    return __int_as_float(__builtin_amdgcn_readlane(__float_as_int(v), l));
}

__device__ __forceinline__ unsigned short bfu(float f) {
    __hip_bfloat16 h = __float2bfloat16(f);
    return *(unsigned short*)&h;
}

__device__ __forceinline__ unsigned pk2(float a, float b) {
    return (unsigned)bfu(a) | ((unsigned)bfu(b) << 16);
}

// ---------------- prep: weight transposes + bf16 [kw*0.125 ; vw] cat ----------------
__global__ __launch_bounds__(256) void prep_kernel(
    const float* __restrict__ k_w, const float* __restrict__ v_w, const float* __restrict__ q_w,
    const float* __restrict__ wih, const float* __restrict__ whh,
    const float* __restrict__ w1, const float* __restrict__ w2,
    unsigned short* __restrict__ wcat, float* __restrict__ qwT,
    float* __restrict__ wihT, float* __restrict__ whhT,
    float* __restrict__ w1T, float* __restrict__ w2T)
{
    int i0 = blockIdx.x * blockDim.x + threadIdx.x;
    int nthr = gridDim.x * blockDim.x;
    for (int t = i0; t < 8192; t += nthr) {
        int n = t >> 6, k = t & 63;
        float val = (n < 64) ? k_w[n * 64 + k] * 0.125f : v_w[(n - 64) * 64 + k];
        wcat[t] = bfu(val);
    }
    for (int t = i0; t < 4096; t += nthr) {
        int r = t >> 6, c = t & 63;
        qwT[t] = q_w[c * 64 + r];
    }
    for (int t = i0; t < 12288; t += nthr) {
        int r = t / 192, c = t % 192;
        wihT[t] = wih[c * 64 + r];
        whhT[t] = whh[c * 64 + r];
    }
    for (int t = i0; t < 8192; t += nthr) {
        int r = t >> 7, c = t & 127;
        w1T[t] = w1[c * 64 + r];
    }
    for (int t = i0; t < 8192; t += nthr) {
        int r = t >> 6, c = t & 63;
        w2T[t] = w2[c * 128 + r];
    }
}

// ---------------- slots init ----------------
__global__ __launch_bounds__(256) void slots_init_kernel(
    const float* __restrict__ eps, const float* __restrict__ mu,
    const float* __restrict__ lv, float* __restrict__ slots)
{
    int idx = blockIdx.x * blockDim.x + threadIdx.x;
    int d = idx & 63;
    slots[idx] = mu[d] + __expf(0.5f * lv[d]) * eps[idx];
}

// ---------------- phase A: LN + k/v proj via MFMA; k -> [tok][d], v -> [b][d][tok] ----------------
// Block = 256 thr / 128 tokens. LN vectorized float4 (4 tok/wave-iter, 8 shfl / 4 tok).
// Both k and v epilogues go through an LDS fp32 transpose (overlaying Xs/Ws) to get
// 16B-coalesced global stores.
__global__ __launch_bounds__(256) void phase_a_mfma(
    const float* __restrict__ inp, const unsigned short* __restrict__ wcat,
    const float* __restrict__ niw, const float* __restrict__ nib,
    unsigned short* __restrict__ kbu, unsigned short* __restrict__ vbt)
{
    __shared__ short smemA[18432];           // 36,864 B
    short* Xs = smemA;                       // [128][72] bf16
    short* Ws = smemA + 9216;                // [128][72] bf16
    float* tbuf = (float*)smemA;             // overlay: k [128][68] f32 (34,816 B) / v [64][132] f32
    const int tid = threadIdx.x, lane = tid & 63, widx = tid >> 6;

    // stage weights
    {
        const unsigned* wg = (const unsigned*)wcat;
        #pragma unroll 4
        for (int t = tid; t < 4096; t += 256) {
            int n = t >> 5, kp = t & 31;
            *(unsigned*)&Ws[n * 72 + kp * 2] = wg[t];
        }
    }

    // LN: lane = (token-in-group:2)(d-quarter:4); 4 tokens per wave-iteration
    const int tg = lane >> 4, dq = lane & 15;
    const float4 wni = *(const float4*)&niw[dq * 4];
    const float4 bni = *(const float4*)&nib[dq * 4];
    const int tok0 = blockIdx.x * 128;
    #pragma unroll
    for (int it = 0; it < 8; ++it) {
        const int m = widx * 32 + it * 4 + tg;
        float4 x = *(const float4*)&inp[(size_t)(tok0 + m) * 64 + dq * 4];
        float s1 = x.x + x.y + x.z + x.w;
        float s2 = fmaf(x.x, x.x, fmaf(x.y, x.y, fmaf(x.z, x.z, x.w * x.w)));
        #pragma unroll
        for (int o = 1; o < 16; o <<= 1) { s1 += __shfl_xor(s1, o); s2 += __shfl_xor(s2, o); }
        float mean = s1 * (1.0f / 64.0f);
        float var = s2 * (1.0f / 64.0f) - mean * mean;
        float rstd = rsqrtf(var + 1e-5f);
        float y0 = (x.x - mean) * rstd * wni.x + bni.x;
        float y1 = (x.y - mean) * rstd * wni.y + bni.y;
        float y2 = (x.z - mean) * rstd * wni.z + bni.z;
        float y3 = (x.w - mean) * rstd * wni.w + bni.w;
        uint2 p; p.x = pk2(y0, y1); p.y = pk2(y2, y3);
        *(uint2*)&Xs[m * 72 + dq * 4] = p;
    }
    __syncthreads();

    const int quad = lane >> 4, l16 = lane & 15;
    short8 afr[2][2];
    #pragma unroll
    for (int mt = 0; mt < 2; ++mt)
        #pragma unroll
        for (int ks = 0; ks < 2; ++ks)
            afr[mt][ks] = *(const short8*)&Xs[(widx * 32 + mt * 16 + l16) * 72 + ks * 32 + quad * 8];

    f32x4 acc[2][8];
    #pragma unroll
    for (int mt = 0; mt < 2; ++mt)
        #pragma unroll
        for (int nt = 0; nt < 8; ++nt)
            acc[mt][nt] = (f32x4){0.f, 0.f, 0.f, 0.f};

    #pragma unroll
    for (int nt = 0; nt < 8; ++nt) {
        #pragma unroll
        for (int ks = 0; ks < 2; ++ks) {
            short8 bfr = *(const short8*)&Ws[(nt * 16 + l16) * 72 + ks * 32 + quad * 8];
            acc[0][nt] = __builtin_amdgcn_mfma_f32_16x16x32_bf16(afr[0][ks], bfr, acc[0][nt], 0, 0, 0);
            acc[1][nt] = __builtin_amdgcn_mfma_f32_16x16x32_bf16(afr[1][ks], bfr, acc[1][nt], 0, 0, 0);
        }
    }

    // ---- k epilogue: LDS fp32 transpose [128 tok][68] -> coalesced dwordx4 stores ----
    __syncthreads();   // all Xs/Ws reads done
    #pragma unroll
    for (int mt = 0; mt < 2; ++mt)
        #pragma unroll
        for (int nt = 0; nt < 4; ++nt)
            #pragma unroll
            for (int r = 0; r < 4; ++r)
                tbuf[(widx * 32 + mt * 16 + quad * 4 + r) * 68 + nt * 16 + l16] = acc[mt][nt][r];
    __syncthreads();
    {
        const int row = tid >> 1, half = tid & 1;
        #pragma unroll
        for (int c = 0; c < 4; ++c) {
            float4 f0 = *(float4*)&tbuf[row * 68 + half * 32 + c * 8];
            float4 f1 = *(float4*)&tbuf[row * 68 + half * 32 + c * 8 + 4];
            uint4 o;
            o.x = pk2(f0.x, f0.y); o.y = pk2(f0.z, f0.w);
            o.z = pk2(f1.x, f1.y); o.w = pk2(f1.z, f1.w);
            *(uint4*)&kbu[(size_t)(tok0 + row) * 64 + half * 32 + c * 8] = o;
        }
    }

    // ---- v epilogue: LDS fp32 transpose [64 d][132] -> vbt[b][d][tok] ----
    __syncthreads();
    #pragma unroll
    for (int mt = 0; mt < 2; ++mt)
        #pragma unroll
        for (int nt = 4; nt < 8; ++nt)
            #pragma unroll
            for (int r = 0; r < 4; ++r)
                tbuf[((nt - 4) * 16 + l16) * 132 + widx * 32 + mt * 16 + quad * 4 + r] = acc[mt][nt][r];
    __syncthreads();
    {
        const int b = blockIdx.x >> 5, tin = (blockIdx.x & 31) * 128;
        const int d = tid >> 2, q4 = tid & 3;
        #pragma unroll
        for (int c = 0; c < 4; ++c) {
            float4 f0 = *(float4*)&tbuf[d * 132 + q4 * 32 + c * 8];
            float4 f1 = *(float4*)&tbuf[d * 132 + q4 * 32 + c * 8 + 4];
            uint4 o;
            o.x = pk2(f0.x, f0.y); o.y = pk2(f0.z, f0.w);
            o.z = pk2(f1.x, f1.y); o.w = pk2(f1.z, f1.w);
            *(uint4*)&vbt[((size_t)b * 64 + d) * 4096 + tin + q4 * 32 + c * 8] = o;
        }
    }
}

// ---------------- q = LN(slots) @ q_w.T -> bf16 ----------------
__global__ __launch_bounds__(256) void q_kernel(
    const float* __restrict__ slots, const float* __restrict__ qwT,
    const float* __restrict__ nsw, const float* __restrict__ nsb,
    unsigned short* __restrict__ qout)
{
    const int lane = threadIdx.x & 63;
    const int row = blockIdx.x * 4 + (threadIdx.x >> 6);
    float x = slots[row * 64 + lane];
    float m = warp_red_sum(x) * (1.0f / 64.0f);
    float dx = x - m;
    float var = warp_red_sum(dx * dx) * (1.0f / 64.0f);
    float xln = dx * rsqrtf(var + 1e-5f) * nsw[lane] + nsb[lane];
    float acc = 0.f;
    #pragma unroll 16
    for (int i = 0; i < 64; ++i) acc = fmaf(bcastlane(xln, i), qwT[i * 64 + lane], acc);
    qout[row * 64 + lane] = bfu(acc);
}

// ---------------- attention via MFMA: QK^T -> softmax -> w^T @ v ----------------
__global__ __launch_bounds__(256) void attn_mfma(
    const __hip_bfloat16* __restrict__ kb, const unsigned short* __restrict__ vbt,
    const unsigned short* __restrict__ qb,
    float* __restrict__ numer, float* __restrict__ denom, float* __restrict__ wout)
{
    __shared__ unsigned short smem[24192];
    unsigned short* Qs = smem;                          // [16][72]
    const int tid = threadIdx.x, lane = tid & 63, widx = tid >> 6;
    unsigned short* wls = smem + 1152 + widx * 1152;    // [16][72]
    unsigned short* vt  = smem + 5760 + widx * 4608;    // [64][72]
    const int b = blockIdx.y;

    for (int t = tid; t < 1024; t += 256) {
        int s = t >> 6, dd = t & 63;
        Qs[s * 72 + dd] = (s < 8) ? qb[b * 512 + t] : (unsigned short)0;
    }
    for (int t = lane; t < 576; t += 64) wls[576 + t] = 0;
    __syncthreads();

    const int quad = lane >> 4, l16 = lane & 15;
    short8 bq0 = *(const short8*)&Qs[l16 * 72 + quad * 8];
    short8 bq1 = *(const short8*)&Qs[l16 * 72 + 32 + quad * 8];

    f32x4 accv[4];
    #pragma unroll
    for (int nt = 0; nt < 4; ++nt) accv[nt] = (f32x4){0.f, 0.f, 0.f, 0.f};
    float dsum = 0.f;

    const int twave0 = blockIdx.x * 512 + widx * 128;
    const int vd = lane >> 3, vc = (lane & 7) * 8;
    #pragma unroll
    for (int iter = 0; iter < 2; ++iter) {
        const int t0 = twave0 + iter * 64;
        uint4 vld[8];
        #pragma unroll
        for (int i = 0; i < 8; ++i)
            vld[i] = *(const uint4*)&vbt[((size_t)b * 64 + i * 8 + vd) * 4096 + t0 + vc];

        #pragma unroll
        for (int t4 = 0; t4 < 4; ++t4) {
            const size_t krow = ((size_t)b * NN + t0 + t4 * 16 + l16) * 64;
            short8 ak0 = *(const short8*)&kb[krow + quad * 8];
            short8 ak1 = *(const short8*)&kb[krow + 32 + quad * 8];
            f32x4 lg = (f32x4){0.f, 0.f, 0.f, 0.f};
            lg = __builtin_amdgcn_mfma_f32_16x16x32_bf16(ak0, bq0, lg, 0, 0, 0);
            lg = __builtin_amdgcn_mfma_f32_16x16x32_bf16(ak1, bq1, lg, 0, 0, 0);
            float wv[4];
            #pragma unroll
            for (int r = 0; r < 4; ++r) {
                float e = __expf(lg[r]);
                float s = e;
                s += __shfl_xor(s, 1); s += __shfl_xor(s, 2); s += __shfl_xor(s, 4);
                wv[r] = e / s + 1e-8f;
                dsum += wv[r];
            }
            if (l16 < 8) {
                *(unsigned*)&wls[l16 * 72 + t4 * 16 + quad * 4]     = pk2(wv[0], wv[1]);
                *(unsigned*)&wls[l16 * 72 + t4 * 16 + quad * 4 + 2] = pk2(wv[2], wv[3]);
                if (wout) {
                    float* wp = wout + ((size_t)b * NN + t0 + t4 * 16 + quad * 4) * 8 + l16;
                    wp[0] = wv[0]; wp[8] = wv[1]; wp[16] = wv[2]; wp[24] = wv[3];
                }
            }
        }
        #pragma unroll
        for (int i = 0; i < 8; ++i)
            *(uint4*)&vt[(i * 8 + vd) * 72 + vc] = vld[i];
        #pragma unroll
        for (int ks = 0; ks < 2; ++ks) {
            short8 aw = *(const short8*)&wls[l16 * 72 + ks * 32 + quad * 8];
            #pragma unroll
            for (int nt = 0; nt < 4; ++nt) {
                short8 bv = *(const short8*)&vt[(nt * 16 + l16) * 72 + ks * 32 + quad * 8];
                accv[nt] = __builtin_amdgcn_mfma_f32_16x16x32_bf16(aw, bv, accv[nt], 0, 0, 0);
            }
        }
    }
    dsum += __shfl_xor(dsum, 16);
    dsum += __shfl_xor(dsum, 32);
    __syncthreads();
    float* red = (float*)(smem + 5760);
    float* dred = red + 2048;
    if (quad < 2) {
        #pragma unroll
        for (int nt = 0; nt < 4; ++nt)
            #pragma unroll
            for (int r = 0; r < 4; ++r)
                red[widx * 512 + (quad * 4 + r) * 64 + nt * 16 + l16] = accv[nt][r];
    }
    if (quad == 0 && l16 < 8) dred[widx * 8 + l16] = dsum;
    __syncthreads();
    for (int e = tid; e < 512; e += 256)
        atomicAdd(numer + (size_t)b * 512 + e, red[e] + red[512 + e] + red[1024 + e] + red[1536 + e]);
    if (tid < 8)
        atomicAdd(denom + b * 8 + tid, dred[tid] + dred[8 + tid] + dred[16 + tid] + dred[24 + tid]);
}

// ---------------- GRU + MLP per slot row ----------------
__global__ __launch_bounds__(256) void gru_kernel(
    const float* __restrict__ numer, const float* __restrict__ denom,
    const float* __restrict__ slotsIn,
    const float* __restrict__ wihT, const float* __restrict__ whhT,
    const float* __restrict__ w1T, const float* __restrict__ w2T,
    const float* __restrict__ bih, const float* __restrict__ bhh,
    const float* __restrict__ nrw, const float* __restrict__ nrb,
    const float* __restrict__ b2, float* __restrict__ slotsOut)
{
    const int lane = threadIdx.x & 63;
    const int row = blockIdx.x * 4 + (threadIdx.x >> 6);
    float x = numer[row * 64 + lane] / denom[row];
    float h = slotsIn[row * 64 + lane];
    float air = 0, aiz = 0, ain = 0, ahr = 0, ahz = 0, ahn = 0;
    #pragma unroll 8
    for (int i = 0; i < 64; ++i) {
        float xi = bcastlane(x, i), hi = bcastlane(h, i);
        const float* wi = wihT + i * 192;
        const float* wh = whhT + i * 192;
        air = fmaf(xi, wi[lane], air);
        aiz = fmaf(xi, wi[64 + lane], aiz);
        ain = fmaf(xi, wi[128 + lane], ain);
        ahr = fmaf(hi, wh[lane], ahr);
        ahz = fmaf(hi, wh[64 + lane], ahz);
        ahn = fmaf(hi, wh[128 + lane], ahn);
    }
    air += bih[lane]; aiz += bih[64 + lane]; ain += bih[128 + lane];
    ahr += bhh[lane]; ahz += bhh[64 + lane]; ahn += bhh[128 + lane];
    float r = 1.f / (1.f + __expf(-(air + ahr)));
    float z = 1.f / (1.f + __expf(-(aiz + ahz)));
    float n = tanhf(ain + r * ahn);
    float hn = (1.f - z) * n + z * h;
    float m = warp_red_sum(hn) * (1.0f / 64.0f);
    float dx = hn - m;
    float var = warp_red_sum(dx * dx) * (1.0f / 64.0f);
    float u = dx * rsqrtf(var + 1e-5f) * nrw[lane] + nrb[lane];
    float o0 = 0.f, o1 = 0.f;
    #pragma unroll 8
    for (int i = 0; i < 64; ++i) {
        float ui = bcastlane(u, i);
        const float* w1r = w1T + i * 128;
        o0 = fmaf(ui, w1r[lane], o0);
        o1 = fmaf(ui, w1r[64 + lane], o1);
    }
    o0 = fmaxf(o0, 0.f); o1 = fmaxf(o1, 0.f);
    float y = 0.f;
    #pragma unroll 8
    for (int j = 0; j < 64; ++j) y = fmaf(bcastlane(o0, j), w2T[j * 64 + lane], y);
    #pragma unroll 8
    for (int j = 0; j < 64; ++j) y = fmaf(bcastlane(o1, j), w2T[(64 + j) * 64 + lane], y);
    y += b2[lane];
    slotsOut[row * 64 + lane] = hn + y;
}

// ---------------- final renorm of w output ----------------
__global__ __launch_bounds__(256) void renorm_kernel(float* __restrict__ wout,
                                                     const float* __restrict__ denom)
{
    const size_t i4 = (size_t)blockIdx.x * blockDim.x + threadIdx.x;
    const size_t b = i4 >> 13;
    const int half = (int)(i4 & 1);
    float4 v = reinterpret_cast<float4*>(wout)[i4];
    const float4 dv = reinterpret_cast<const float4*>(denom)[b * 2 + half];
    v.x /= dv.x; v.y /= dv.y; v.z /= dv.z; v.w /= dv.w;
    reinterpret_cast<float4*>(wout)[i4] = v;
}

extern "C" void kernel_launch(void* const* d_in, const int* in_sizes, int n_in,
                              void* d_out, int out_size, void* d_ws, size_t ws_size,
                              hipStream_t stream)
{
    const float* inputs  = (const float*)d_in[0];
    const float* eps_n   = (const float*)d_in[1];
    const float* mu      = (const float*)d_in[2];
    const float* lv      = (const float*)d_in[3];
    const float* k_w     = (const float*)d_in[4];
    const float* v_w     = (const float*)d_in[5];
    const float* q_w     = (const float*)d_in[6];
    const float* ni_w    = (const float*)d_in[7];
    const float* ni_b    = (const float*)d_in[8];
    const float* ns_w    = (const float*)d_in[9];
    const float* ns_b    = (const float*)d_in[10];
    const float* nr_w    = (const float*)d_in[11];
    const float* nr_b    = (const float*)d_in[12];
    const float* gru_wih = (const float*)d_in[13];
    const float* gru_whh = (const float*)d_in[14];
    const float* gru_bih = (const float*)d_in[15];
    const float* gru_bhh = (const float*)d_in[16];
    const float* mlp_w1  = (const float*)d_in[17];
    const float* mlp_w2  = (const float*)d_in[18];
    const float* mlp_b2  = (const float*)d_in[19];

    char* wsb = (char*)d_ws;
    __hip_bfloat16* kb  = (__hip_bfloat16*)wsb;                    // [B][N][64] bf16
    unsigned short* vbt = (unsigned short*)(wsb + 67108864);       // [B][64][N] bf16 (transposed)
    float* f      = (float*)(wsb + 134217728);
    float* slotsA = f;                  // 65536
    float* slotsB = f + 65536;          // 65536
    unsigned short* qb = (unsigned short*)(f + 131072);  // [B][8][64] bf16
    float* numer  = f + 196608;         // 65536
    float* denom  = f + 262144;         // 1024
    unsigned short* wcat = (unsigned short*)(f + 263168);  // 8192 bf16
    float* qwT    = f + 263168 + 4096;  // 4096
    float* wihT   = qwT + 4096;
    float* whhT   = wihT + 12288;
    float* w1T    = whhT + 12288;
    float* w2T    = w1T + 8192;

    float* out_slots = (float*)d_out;
    float* out_w     = out_slots + 65536;

    prep_kernel<<<64, 256, 0, stream>>>(k_w, v_w, q_w, gru_wih, gru_whh, mlp_w1, mlp_w2,
                                        wcat, qwT, wihT, whhT, w1T, w2T);
    slots_init_kernel<<<256, 256, 0, stream>>>(eps_n, mu, lv, slotsA);
    phase_a_mfma<<<4096, 256, 0, stream>>>(inputs, wcat, ni_w, ni_b,
                                           (unsigned short*)kb, vbt);

    float* cur = slotsA;
    for (int step = 0; step < 4; ++step) {
        hipMemsetAsync(numer, 0, (65536 + 1024) * sizeof(float), stream);
        q_kernel<<<256, 256, 0, stream>>>(cur, qwT, ns_w, ns_b, qb);
        attn_mfma<<<dim3(8, 128), 256, 0, stream>>>(kb, vbt, qb, numer, denom,
                                                    step == 3 ? out_w : nullptr);
        float* nxt = (step == 3) ? out_slots : ((step & 1) ? slotsA : slotsB);
        gru_kernel<<<256, 256, 0, stream>>>(numer, denom, cur, wihT, whhT, w1T, w2T,
                                            gru_bih, gru_bhh, nr_w, nr_b, mlp_b2, nxt);
        cur = nxt;
    }
    renorm_kernel<<<4096, 256, 0, stream>>>(out_w, denom);
}